// Round 4
// baseline (730.426 us; speedup 1.0000x reference)
//
#include <hip/hip_runtime.h>

#define NPTS   262144
#define NBALLS 8192
#define MSZ    32

typedef unsigned short u16;
typedef __attribute__((ext_vector_type(8))) unsigned short u16x8;
typedef __attribute__((ext_vector_type(4))) unsigned short u16x4;
typedef __attribute__((ext_vector_type(8))) __bf16 bf16x8;
typedef __attribute__((ext_vector_type(4))) float f32x4;

__device__ inline u16 f2bf(float f) {
    unsigned u = __builtin_bit_cast(unsigned, f);
    u += 0x7fffu + ((u >> 16) & 1u);           // RNE
    return (u16)(u >> 16);
}

__device__ inline f32x4 mfma16(u16x8 a, u16x8 b, f32x4 c) {
    return __builtin_amdgcn_mfma_f32_16x16x32_bf16(
        __builtin_bit_cast(bf16x8, a), __builtin_bit_cast(bf16x8, b), c, 0, 0, 0);
}

// ---------------- K0: weight prep (round-1 verified, unchanged) --------------
// new qkv col index cp = mat*256 + h*32 + e  <->  orig col = h*96 + e*3 + mat
__global__ __launch_bounds__(256) void k0_wprep(const float* __restrict__ w_qkv,
                                                const float* __restrict__ b_qkv,
                                                const float* __restrict__ w_proj,
                                                u16* __restrict__ wqkvT,
                                                u16* __restrict__ wprojT,
                                                float* __restrict__ bq) {
    int idx = blockIdx.x * 256 + threadIdx.x;
    if (idx < 768 * 256) {
        int cp = idx >> 8, r = idx & 255;
        int k = cp >> 8, rem = cp & 255, h = rem >> 5, e = rem & 31;
        int orig = h * 96 + e * 3 + k;
        wqkvT[cp * 256 + r] = f2bf(w_qkv[r * 768 + orig]);
        if (r == 0) bq[cp] = b_qkv[orig];
    } else {
        int i2 = idx - 768 * 256;
        if (i2 < 256 * 256) {
            int c = i2 >> 8, r = i2 & 255;
            wprojT[c * 256 + r] = f2bf(w_proj[r * 256 + c]);
        }
    }
}

// ---------------- K0b: xp = bf16(x + rel@w_pe + b_pe)  (round-1 verified) ----
__global__ __launch_bounds__(256) void k0b_xp(const float* __restrict__ x,
                                              const float* __restrict__ pos,
                                              const float* __restrict__ w_pe,
                                              const float* __restrict__ b_pe,
                                              u16* __restrict__ xp) {
    int ball = blockIdx.x, t = threadIdx.x;
    __shared__ float ps[MSZ][3];
    __shared__ float ctr[3];
    if (t < MSZ * 3) ((float*)ps)[t] = pos[(size_t)ball * (MSZ * 3) + t];
    __syncthreads();
    if (t < 3) {
        float s = 0.f;
#pragma unroll
        for (int j = 0; j < MSZ; ++j) s += ps[j][t];
        ctr[t] = s * (1.0f / MSZ);
    }
    __syncthreads();
    int c4 = (t & 63) * 4;
    float4 w0 = *(const float4*)&w_pe[c4];
    float4 w1 = *(const float4*)&w_pe[256 + c4];
    float4 w2 = *(const float4*)&w_pe[512 + c4];
    float4 bp = *(const float4*)&b_pe[c4];
#pragma unroll
    for (int mi = (t >> 6); mi < MSZ; mi += 4) {
        float rx = ps[mi][0] - ctr[0], ry = ps[mi][1] - ctr[1], rz = ps[mi][2] - ctr[2];
        size_t row = (size_t)ball * MSZ + mi;
        float4 xv = *(const float4*)&x[row * 256 + c4];
        u16x4 o;
        o.x = f2bf(xv.x + rx * w0.x + ry * w1.x + rz * w2.x + bp.x);
        o.y = f2bf(xv.y + rx * w0.y + ry * w1.y + rz * w2.y + bp.y);
        o.z = f2bf(xv.z + rx * w0.z + ry * w1.z + rz * w2.z + bp.z);
        o.w = f2bf(xv.w + rx * w0.w + ry * w1.w + rz * w2.w + bp.w);
        *(u16x4*)&xp[row * 256 + c4] = o;
    }
}

// ---------------- Fused per-ball: QKV gemm + attention + proj ----------------
// 2 balls/block, 4 waves/ball. All fragment paths are round-1-verified.
__global__ __launch_bounds__(512, 1) void k_ball(const u16* __restrict__ xp,
                                                 const u16* __restrict__ wqkvT,
                                                 const u16* __restrict__ wprojT,
                                                 const float* __restrict__ bq,
                                                 const float* __restrict__ bp,
                                                 const float* __restrict__ pos,
                                                 const float* __restrict__ sigma,
                                                 float* __restrict__ out) {
    __shared__ __align__(16) u16 qk_s[2][MSZ][520];   // Q cols 0..255 (later attn-out), K cols 256..511
    __shared__ __align__(16) u16 V_s[2][MSZ][256];    // swizzled (round-1 pattern)
    __shared__ __align__(16) u16 P_s[8][MSZ][40];
    __shared__ float dist_s[2][MSZ][33];
    __shared__ float ps_s[2][MSZ][3];

    const int t = threadIdx.x;
    const int lane = t & 63, wv = t >> 6;
    const int r15 = lane & 15, g4 = lane >> 4;
    const int sub = wv >> 2, wq = wv & 3;             // ball-slot, wave-within-ball
    const int ball = blockIdx.x * 2 + sub;
    const size_t ballu16 = (size_t)ball * (MSZ * 256);

    if (t < 192) ((float*)ps_s)[t] = pos[(size_t)blockIdx.x * 192 + t];

    // xp A-frags: af[pi][ks] — lane r15 = row(point), elems = k (g4*8..+7)
    u16x8 af[2][8];
#pragma unroll
    for (int pi = 0; pi < 2; ++pi)
#pragma unroll
        for (int ks = 0; ks < 8; ++ks)
            af[pi][ks] = *(const u16x8*)&xp[ballu16 + (size_t)(pi * 16 + r15) * 256 + ks * 32 + g4 * 8];

    __syncthreads();                                  // ps_s ready

    // distance tables (threads 0..255 -> ball slot 0; 256..511 -> slot 1)
    {
        int sb = t >> 8;
        for (int p = (t & 255); p < 1024; p += 256) {
            int m = p >> 5, k = p & 31;
            float dx = ps_s[sb][m][0] - ps_s[sb][k][0];
            float dy = ps_s[sb][m][1] - ps_s[sb][k][1];
            float dz = ps_s[sb][m][2] - ps_s[sb][k][2];
            dist_s[sb][m][k] = sqrtf(fmaxf(dx * dx + dy * dy + dz * dz, 1e-12f));
        }
    }

    // ---- QKV GEMM: wave computes permuted cols [wq*192, wq*192+192) ----
    for (int tile = 0; tile < 12; ++tile) {
        int c0 = wq * 192 + tile * 16;
        f32x4 a0 = {0.f, 0.f, 0.f, 0.f}, a1 = {0.f, 0.f, 0.f, 0.f};
#pragma unroll
        for (int ks = 0; ks < 8; ++ks) {
            u16x8 b = *(const u16x8*)&wqkvT[(size_t)(c0 + r15) * 256 + ks * 32 + g4 * 8];
            a0 = mfma16(af[0][ks], b, a0);
            a1 = mfma16(af[1][ks], b, a1);
        }
        int f = c0 + r15;
        float bias = bq[f];
#pragma unroll
        for (int i = 0; i < 2; ++i) {
            f32x4 av = i ? a1 : a0;
#pragma unroll
            for (int r = 0; r < 4; ++r) {
                int m = i * 16 + g4 * 4 + r;
                u16 hv = f2bf(av[r] + bias);
                if (f < 512) qk_s[sub][m][f] = hv;
                else         V_s[sub][m][(f - 512) ^ (((m >> 3) & 3) << 4)] = hv;
            }
        }
    }
    __syncthreads();                                  // qkv + dist ready

    // ---- attention: wave handles heads 2wq, 2wq+1 (round-1 k2 verbatim) ----
    const float scale = 0.17677669529663687f;         // 1/sqrt(32)
#pragma unroll
    for (int hh = 0; hh < 2; ++hh) {
        int h = wq * 2 + hh;
        float sig = sigma[h];
        u16x8 aq[2], bk[2];
#pragma unroll
        for (int i = 0; i < 2; ++i) {
            aq[i] = *(const u16x8*)&qk_s[sub][i * 16 + r15][h * 32 + g4 * 8];
            bk[i] = *(const u16x8*)&qk_s[sub][i * 16 + r15][256 + h * 32 + g4 * 8];
        }
        f32x4 s[2][2];
#pragma unroll
        for (int i = 0; i < 2; ++i)
#pragma unroll
            for (int j = 0; j < 2; ++j) s[i][j] = (f32x4){0.f, 0.f, 0.f, 0.f};
#pragma unroll
        for (int i = 0; i < 2; ++i)
#pragma unroll
            for (int j = 0; j < 2; ++j)
                s[i][j] = mfma16(aq[i], bk[j], s[i][j]);

#pragma unroll
        for (int i = 0; i < 2; ++i) {
#pragma unroll
            for (int r = 0; r < 4; ++r) {
                int row = i * 16 + g4 * 4 + r;
                float v0 = s[i][0][r] * scale + sig * dist_s[sub][row][r15];
                float v1 = s[i][1][r] * scale + sig * dist_s[sub][row][16 + r15];
                float m = fmaxf(v0, v1);
                m = fmaxf(m, __shfl_xor(m, 1));
                m = fmaxf(m, __shfl_xor(m, 2));
                m = fmaxf(m, __shfl_xor(m, 4));
                m = fmaxf(m, __shfl_xor(m, 8));
                float e0 = __expf(v0 - m), e1 = __expf(v1 - m);
                float su = e0 + e1;
                su += __shfl_xor(su, 1);
                su += __shfl_xor(su, 2);
                su += __shfl_xor(su, 4);
                su += __shfl_xor(su, 8);
                float rin = 1.0f / su;
                P_s[wv][row][r15]      = f2bf(e0 * rin);
                P_s[wv][row][16 + r15] = f2bf(e1 * rin);
            }
        }
        u16x8 pa[2];
#pragma unroll
        for (int i = 0; i < 2; ++i)
            pa[i] = *(const u16x8*)&P_s[wv][i * 16 + r15][g4 * 8];
        u16x8 bv[2];
#pragma unroll
        for (int j = 0; j < 2; ++j) {
#pragma unroll
            for (int jj = 0; jj < 8; ++jj) {
                int kp = g4 * 8 + jj;
                int colv = h * 32 + j * 16 + r15;
                bv[j][jj] = V_s[sub][kp][colv ^ (((kp >> 3) & 3) << 4)];
            }
        }
        f32x4 o[2][2];
#pragma unroll
        for (int i = 0; i < 2; ++i)
#pragma unroll
            for (int j = 0; j < 2; ++j) o[i][j] = (f32x4){0.f, 0.f, 0.f, 0.f};
#pragma unroll
        for (int i = 0; i < 2; ++i)
#pragma unroll
            for (int j = 0; j < 2; ++j)
                o[i][j] = mfma16(pa[i], bv[j], o[i][j]);
        // attn-out -> q-region cols of head h (only this wave reads those cols)
#pragma unroll
        for (int i = 0; i < 2; ++i)
#pragma unroll
            for (int j = 0; j < 2; ++j)
#pragma unroll
                for (int r = 0; r < 4; ++r) {
                    int row = i * 16 + g4 * 4 + r;
                    int col = h * 32 + j * 16 + r15;
                    qk_s[sub][row][col] = f2bf(o[i][j][r]);
                }
    }
    __syncthreads();                                  // all heads' attn-out ready

    // ---- proj: wave computes out cols [wq*64, wq*64+64) (round-1 k3 pattern) ----
    f32x4 pacc[4][2];
#pragma unroll
    for (int tt = 0; tt < 4; ++tt)
#pragma unroll
        for (int i = 0; i < 2; ++i) pacc[tt][i] = (f32x4){0.f, 0.f, 0.f, 0.f};
#pragma unroll
    for (int hk = 0; hk < 8; ++hk) {
        u16x8 apj[2];
#pragma unroll
        for (int i = 0; i < 2; ++i)
            apj[i] = *(const u16x8*)&qk_s[sub][i * 16 + r15][hk * 32 + g4 * 8];
#pragma unroll
        for (int tt = 0; tt < 4; ++tt) {
            int ct = (wq * 4 + tt) * 16;
            u16x8 b = *(const u16x8*)&wprojT[(size_t)(ct + r15) * 256 + hk * 32 + g4 * 8];
            pacc[tt][0] = mfma16(apj[0], b, pacc[tt][0]);
            pacc[tt][1] = mfma16(apj[1], b, pacc[tt][1]);
        }
    }
#pragma unroll
    for (int tt = 0; tt < 4; ++tt) {
        int ct = (wq * 4 + tt) * 16;
        float bb = bp[ct + r15];
#pragma unroll
        for (int i = 0; i < 2; ++i)
#pragma unroll
            for (int r = 0; r < 4; ++r) {
                int row = ball * MSZ + i * 16 + g4 * 4 + r;
                out[(size_t)row * 256 + ct + r15] = pacc[tt][i][r] + bb;
            }
    }
}

extern "C" void kernel_launch(void* const* d_in, const int* in_sizes, int n_in,
                              void* d_out, int out_size, void* d_ws, size_t ws_size,
                              hipStream_t stream) {
    (void)in_sizes; (void)n_in; (void)out_size; (void)ws_size;
    const float* x      = (const float*)d_in[0];
    const float* pos    = (const float*)d_in[1];
    const float* w_qkv  = (const float*)d_in[2];
    const float* b_qkv  = (const float*)d_in[3];
    const float* w_pe   = (const float*)d_in[4];
    const float* b_pe   = (const float*)d_in[5];
    const float* w_proj = (const float*)d_in[6];
    const float* b_proj = (const float*)d_in[7];
    const float* sigma  = (const float*)d_in[8];
    float* out = (float*)d_out;

    u16* xp     = (u16*)d_ws;                         // N*256 bf16 = 134 MB
    u16* wqkvT  = xp + (size_t)NPTS * 256;            // 768*256 u16
    u16* wprojT = wqkvT + 768 * 256;                  // 256*256 u16
    float* bq   = (float*)(wprojT + 256 * 256);       // 768 f32

    k0_wprep<<<1024, 256, 0, stream>>>(w_qkv, b_qkv, w_proj, wqkvT, wprojT, bq);
    k0b_xp<<<NBALLS, 256, 0, stream>>>(x, pos, w_pe, b_pe, xp);
    k_ball<<<NBALLS / 2, 512, 0, stream>>>(xp, wqkvT, wprojT, bq, b_proj, pos, sigma, out);
}

// Round 5
// 558.471 us; speedup vs baseline: 1.3079x; 1.3079x over previous
//
#include <hip/hip_runtime.h>

#define NPTS   262144
#define NBALLS 8192
#define MSZ    32

typedef unsigned short u16;
typedef __attribute__((ext_vector_type(8))) unsigned short u16x8;
typedef __attribute__((ext_vector_type(4))) unsigned short u16x4;
typedef __attribute__((ext_vector_type(8))) __bf16 bf16x8;
typedef __attribute__((ext_vector_type(4))) float f32x4;

__device__ inline u16 f2bf(float f) {
    unsigned u = __builtin_bit_cast(unsigned, f);
    u += 0x7fffu + ((u >> 16) & 1u);           // RNE
    return (u16)(u >> 16);
}

__device__ inline f32x4 mfma16(u16x8 a, u16x8 b, f32x4 c) {
    return __builtin_amdgcn_mfma_f32_16x16x32_bf16(
        __builtin_bit_cast(bf16x8, a), __builtin_bit_cast(bf16x8, b), c, 0, 0, 0);
}

__device__ inline void gload_lds16(const u16* g, u16* l) {
    __builtin_amdgcn_global_load_lds(
        (const __attribute__((address_space(1))) void*)g,
        (__attribute__((address_space(3))) void*)l, 16, 0, 0);
}

// ---------------- K0: weight prep (round-1 verified, unchanged) --------------
__global__ __launch_bounds__(256) void k0_wprep(const float* __restrict__ w_qkv,
                                                const float* __restrict__ b_qkv,
                                                const float* __restrict__ w_proj,
                                                u16* __restrict__ wqkvT,
                                                u16* __restrict__ wprojT,
                                                float* __restrict__ bq) {
    int idx = blockIdx.x * 256 + threadIdx.x;
    if (idx < 768 * 256) {
        int cp = idx >> 8, r = idx & 255;
        int k = cp >> 8, rem = cp & 255, h = rem >> 5, e = rem & 31;
        int orig = h * 96 + e * 3 + k;
        wqkvT[cp * 256 + r] = f2bf(w_qkv[r * 768 + orig]);
        if (r == 0) bq[cp] = b_qkv[orig];
    } else {
        int i2 = idx - 768 * 256;
        if (i2 < 256 * 256) {
            int c = i2 >> 8, r = i2 & 255;
            wprojT[c * 256 + r] = f2bf(w_proj[r * 256 + c]);
        }
    }
}

// ---------------- K0b: xp = bf16(x + rel@w_pe + b_pe)  (round-1 verified) ----
__global__ __launch_bounds__(256) void k0b_xp(const float* __restrict__ x,
                                              const float* __restrict__ pos,
                                              const float* __restrict__ w_pe,
                                              const float* __restrict__ b_pe,
                                              u16* __restrict__ xp) {
    int ball = blockIdx.x, t = threadIdx.x;
    __shared__ float ps[MSZ][3];
    __shared__ float ctr[3];
    if (t < MSZ * 3) ((float*)ps)[t] = pos[(size_t)ball * (MSZ * 3) + t];
    __syncthreads();
    if (t < 3) {
        float s = 0.f;
#pragma unroll
        for (int j = 0; j < MSZ; ++j) s += ps[j][t];
        ctr[t] = s * (1.0f / MSZ);
    }
    __syncthreads();
    int c4 = (t & 63) * 4;
    float4 w0 = *(const float4*)&w_pe[c4];
    float4 w1 = *(const float4*)&w_pe[256 + c4];
    float4 w2 = *(const float4*)&w_pe[512 + c4];
    float4 bp = *(const float4*)&b_pe[c4];
#pragma unroll
    for (int mi = (t >> 6); mi < MSZ; mi += 4) {
        float rx = ps[mi][0] - ctr[0], ry = ps[mi][1] - ctr[1], rz = ps[mi][2] - ctr[2];
        size_t row = (size_t)ball * MSZ + mi;
        float4 xv = *(const float4*)&x[row * 256 + c4];
        u16x4 o;
        o.x = f2bf(xv.x + rx * w0.x + ry * w1.x + rz * w2.x + bp.x);
        o.y = f2bf(xv.y + rx * w0.y + ry * w1.y + rz * w2.y + bp.y);
        o.z = f2bf(xv.z + rx * w0.z + ry * w1.z + rz * w2.z + bp.z);
        o.w = f2bf(xv.w + rx * w0.w + ry * w1.w + rz * w2.w + bp.w);
        *(u16x4*)&xp[row * 256 + c4] = o;
    }
}

// ---------------- K1: QKV GEMM with T2 XOR-swizzled LDS ---------------------
// LDS granule slot s of row r holds global granule s^(r&7)  (granule = 8 u16)
__global__ __launch_bounds__(256) void k1_qkv(const u16* __restrict__ xp,
                                              const u16* __restrict__ wqkvT,
                                              const float* __restrict__ bq,
                                              u16* __restrict__ qkv) {
    __shared__ __align__(16) u16 As[2][128 * 64];
    __shared__ __align__(16) u16 Bs[2][128 * 64];
    int id = blockIdx.x;
    int wk = (id >> 3) + (id & 7) * 1536;       // bijective XCD swizzle
    int ct = wk % 6, rt = wk / 6;
    int t = threadIdx.x;
    int lane = t & 63, wv = t >> 6;
    int r15 = lane & 15, g4 = lane >> 4;
    int wr = wv >> 1, wc = wv & 1;
    int rowbase = rt * 128, colbase = ct * 128;

    // staging indices (swizzled global source, linear LDS dest)
    const int srow = t >> 3, sg = t & 7;

    f32x4 acc[4][4];
#pragma unroll
    for (int i = 0; i < 4; ++i)
#pragma unroll
        for (int j = 0; j < 4; ++j) acc[i][j] = (f32x4){0.f, 0.f, 0.f, 0.f};

#pragma unroll
    for (int i = 0; i < 4; ++i) {
        int row = i * 32 + srow;
        int gsw = (sg ^ (row & 7)) * 8;
        gload_lds16(&xp[(size_t)(rowbase + row) * 256 + gsw],
                    &As[0][(i * 256 + wv * 64) * 8]);
        gload_lds16(&wqkvT[(size_t)(colbase + row) * 256 + gsw],
                    &Bs[0][(i * 256 + wv * 64) * 8]);
    }
    __syncthreads();

    for (int kt = 0; kt < 4; ++kt) {
        int cur = kt & 1;
        if (kt < 3) {
            int k0 = (kt + 1) * 64;
#pragma unroll
            for (int i = 0; i < 4; ++i) {
                int row = i * 32 + srow;
                int gsw = k0 + (sg ^ (row & 7)) * 8;
                gload_lds16(&xp[(size_t)(rowbase + row) * 256 + gsw],
                            &As[cur ^ 1][(i * 256 + wv * 64) * 8]);
                gload_lds16(&wqkvT[(size_t)(colbase + row) * 256 + gsw],
                            &Bs[cur ^ 1][(i * 256 + wv * 64) * 8]);
            }
        }
#pragma unroll
        for (int ks = 0; ks < 2; ++ks) {
            u16x8 a[4], b[4];
#pragma unroll
            for (int i = 0; i < 4; ++i) {
                int R = wr * 64 + i * 16 + r15;
                a[i] = *(const u16x8*)&As[cur][R * 64 + (((ks * 4 + g4) ^ (R & 7)) * 8)];
            }
#pragma unroll
            for (int j = 0; j < 4; ++j) {
                int R = wc * 64 + j * 16 + r15;
                b[j] = *(const u16x8*)&Bs[cur][R * 64 + (((ks * 4 + g4) ^ (R & 7)) * 8)];
            }
#pragma unroll
            for (int i = 0; i < 4; ++i)
#pragma unroll
                for (int j = 0; j < 4; ++j)
                    acc[i][j] = mfma16(a[i], b[j], acc[i][j]);
        }
        __syncthreads();
    }

#pragma unroll
    for (int j = 0; j < 4; ++j) {
        int col = colbase + wc * 64 + j * 16 + r15;
        float bias = bq[col];
#pragma unroll
        for (int i = 0; i < 4; ++i) {
            int row0 = rowbase + wr * 64 + i * 16 + g4 * 4;
#pragma unroll
            for (int r = 0; r < 4; ++r)
                qkv[(size_t)(row0 + r) * 768 + col] = f2bf(acc[i][j][r] + bias);
        }
    }
}

// ---------------- K23: fused attention + projection, 1 ball/block -----------
__global__ __launch_bounds__(256) void k23_attnproj(const float* __restrict__ pos,
                                                    const float* __restrict__ sigma,
                                                    const u16* __restrict__ qkv,
                                                    const u16* __restrict__ wprojT,
                                                    const float* __restrict__ bp,
                                                    float* __restrict__ out) {
    int ball = blockIdx.x, t = threadIdx.x;
    __shared__ float ps[MSZ][3];
    __shared__ float dist_s[MSZ][33];
    __shared__ __align__(16) u16 V_s[MSZ][256];     // swizzled (round-1 verified)
    __shared__ __align__(16) u16 P_s[4][MSZ][40];
    __shared__ __align__(16) u16 ao_s[MSZ][264];    // attn output (rows x 256, pad 8)

    if (t < MSZ * 3) ((float*)ps)[t] = pos[(size_t)ball * (MSZ * 3) + t];
    __syncthreads();
    for (int p = t; p < 1024; p += 256) {
        int m = p >> 5, k = p & 31;
        float dx = ps[m][0] - ps[k][0], dy = ps[m][1] - ps[k][1], dz = ps[m][2] - ps[k][2];
        dist_s[m][k] = sqrtf(fmaxf(dx * dx + dy * dy + dz * dz, 1e-12f));
    }
    const size_t ballrow = (size_t)ball * MSZ * 768;
#pragma unroll
    for (int i = 0; i < 4; ++i) {
        int c = i * 256 + t;
        int row = c >> 5, col8 = (c & 31) * 8;
        int cs = col8 ^ (((row >> 3) & 3) << 4);
        *(u16x8*)&V_s[row][cs] = *(const u16x8*)&qkv[ballrow + (size_t)row * 768 + 512 + col8];
    }
    __syncthreads();

    int lane = t & 63, wv = t >> 6;
    int r15 = lane & 15, g4 = lane >> 4;
    const float scale = 0.17677669529663687f;       // 1/sqrt(32)

#pragma unroll
    for (int hh = 0; hh < 2; ++hh) {
        int h = wv * 2 + hh;
        float sig = sigma[h];
        u16x8 aq[2], bk[2];
#pragma unroll
        for (int i = 0; i < 2; ++i) {
            aq[i] = *(const u16x8*)&qkv[ballrow + (size_t)(i * 16 + r15) * 768 + h * 32 + g4 * 8];
            bk[i] = *(const u16x8*)&qkv[ballrow + (size_t)(i * 16 + r15) * 768 + 256 + h * 32 + g4 * 8];
        }
        f32x4 s[2][2];
#pragma unroll
        for (int i = 0; i < 2; ++i)
#pragma unroll
            for (int j = 0; j < 2; ++j) s[i][j] = (f32x4){0.f, 0.f, 0.f, 0.f};
#pragma unroll
        for (int i = 0; i < 2; ++i)
#pragma unroll
            for (int j = 0; j < 2; ++j)
                s[i][j] = mfma16(aq[i], bk[j], s[i][j]);

#pragma unroll
        for (int i = 0; i < 2; ++i) {
#pragma unroll
            for (int r = 0; r < 4; ++r) {
                int row = i * 16 + g4 * 4 + r;
                float v0 = s[i][0][r] * scale + sig * dist_s[row][r15];
                float v1 = s[i][1][r] * scale + sig * dist_s[row][16 + r15];
                float m = fmaxf(v0, v1);
                m = fmaxf(m, __shfl_xor(m, 1));
                m = fmaxf(m, __shfl_xor(m, 2));
                m = fmaxf(m, __shfl_xor(m, 4));
                m = fmaxf(m, __shfl_xor(m, 8));
                float e0 = __expf(v0 - m), e1 = __expf(v1 - m);
                float su = e0 + e1;
                su += __shfl_xor(su, 1);
                su += __shfl_xor(su, 2);
                su += __shfl_xor(su, 4);
                su += __shfl_xor(su, 8);
                float rin = 1.0f / su;
                P_s[wv][row][r15]      = f2bf(e0 * rin);
                P_s[wv][row][16 + r15] = f2bf(e1 * rin);
            }
        }
        u16x8 pa[2];
#pragma unroll
        for (int i = 0; i < 2; ++i)
            pa[i] = *(const u16x8*)&P_s[wv][i * 16 + r15][g4 * 8];
        u16x8 bv[2];
#pragma unroll
        for (int j = 0; j < 2; ++j) {
#pragma unroll
            for (int jj = 0; jj < 8; ++jj) {
                int kp = g4 * 8 + jj;
                int colv = h * 32 + j * 16 + r15;
                bv[j][jj] = V_s[kp][colv ^ (((kp >> 3) & 3) << 4)];
            }
        }
        f32x4 o[2][2];
#pragma unroll
        for (int i = 0; i < 2; ++i)
#pragma unroll
            for (int j = 0; j < 2; ++j) o[i][j] = (f32x4){0.f, 0.f, 0.f, 0.f};
#pragma unroll
        for (int i = 0; i < 2; ++i)
#pragma unroll
            for (int j = 0; j < 2; ++j)
                o[i][j] = mfma16(pa[i], bv[j], o[i][j]);
#pragma unroll
        for (int i = 0; i < 2; ++i)
#pragma unroll
            for (int j = 0; j < 2; ++j)
#pragma unroll
                for (int r = 0; r < 4; ++r) {
                    int row = i * 16 + g4 * 4 + r;
                    int col = h * 32 + j * 16 + r15;
                    ao_s[row][col] = f2bf(o[i][j][r]);
                }
    }
    __syncthreads();

    // ---- proj: wave wv computes out cols [wv*64, wv*64+64) ----
    f32x4 pacc[4][2];
#pragma unroll
    for (int tt = 0; tt < 4; ++tt)
#pragma unroll
        for (int i = 0; i < 2; ++i) pacc[tt][i] = (f32x4){0.f, 0.f, 0.f, 0.f};
#pragma unroll
    for (int hk = 0; hk < 8; ++hk) {
        u16x8 apj[2];
#pragma unroll
        for (int i = 0; i < 2; ++i)
            apj[i] = *(const u16x8*)&ao_s[i * 16 + r15][hk * 32 + g4 * 8];
#pragma unroll
        for (int tt = 0; tt < 4; ++tt) {
            int ct = (wv * 4 + tt) * 16;
            u16x8 b = *(const u16x8*)&wprojT[(size_t)(ct + r15) * 256 + hk * 32 + g4 * 8];
            pacc[tt][0] = mfma16(apj[0], b, pacc[tt][0]);
            pacc[tt][1] = mfma16(apj[1], b, pacc[tt][1]);
        }
    }
#pragma unroll
    for (int tt = 0; tt < 4; ++tt) {
        int ct = (wv * 4 + tt) * 16;
        float bb = bp[ct + r15];
#pragma unroll
        for (int i = 0; i < 2; ++i)
#pragma unroll
            for (int r = 0; r < 4; ++r) {
                int row = ball * MSZ + i * 16 + g4 * 4 + r;
                out[(size_t)row * 256 + ct + r15] = pacc[tt][i][r] + bb;
            }
    }
}

extern "C" void kernel_launch(void* const* d_in, const int* in_sizes, int n_in,
                              void* d_out, int out_size, void* d_ws, size_t ws_size,
                              hipStream_t stream) {
    (void)in_sizes; (void)n_in; (void)out_size; (void)ws_size;
    const float* x      = (const float*)d_in[0];
    const float* pos    = (const float*)d_in[1];
    const float* w_qkv  = (const float*)d_in[2];
    const float* b_qkv  = (const float*)d_in[3];
    const float* w_pe   = (const float*)d_in[4];
    const float* b_pe   = (const float*)d_in[5];
    const float* w_proj = (const float*)d_in[6];
    const float* b_proj = (const float*)d_in[7];
    const float* sigma  = (const float*)d_in[8];
    float* out = (float*)d_out;

    u16* qkv    = (u16*)d_ws;                       // N*768 bf16 = 402.7 MB
    u16* wqkvT  = qkv + (size_t)NPTS * 768;
    u16* wprojT = wqkvT + 768 * 256;
    float* bq   = (float*)(wprojT + 256 * 256);
    u16* xp     = (u16*)d_out;                      // scratch in d_out, consumed by k1

    k0_wprep<<<1024, 256, 0, stream>>>(w_qkv, b_qkv, w_proj, wqkvT, wprojT, bq);
    k0b_xp<<<NBALLS, 256, 0, stream>>>(x, pos, w_pe, b_pe, xp);
    k1_qkv<<<12288, 256, 0, stream>>>(xp, wqkvT, bq, qkv);
    k23_attnproj<<<NBALLS, 256, 0, stream>>>(pos, sigma, qkv, wprojT, b_proj, out);
}